// Round 8
// baseline (320.407 us; speedup 1.0000x reference)
//
#include <hip/hip_runtime.h>
#include <hip/hip_bf16.h>
#include <stdint.h>

#define N_USERS   10000
#define N_ITEMS   100000
#define N_FEAT    64
#define EMB_DIM   128
#define SEQ_LEN   50
#define TAU       0.01f
#define SEQ_FLOATS (SEQ_LEN * N_FEAT)   // 3200 floats = 12.8 KB per sequence

typedef float f32x4 __attribute__((ext_vector_type(4)));   // native clang vector

// ---- global->LDS direct DMA (no result VGPRs; 1 KB per wave-op) ----------
// HW semantics: per-lane GLOBAL src address; LDS dest = wave-uniform base +
// lane*size. Address-space casts via uintptr_t (CK's pattern).
__device__ inline void stage16(const float* g, float* l) {
    __builtin_amdgcn_global_load_lds(
        reinterpret_cast<const __attribute__((address_space(1))) void*>(
            reinterpret_cast<uintptr_t>(g)),
        reinterpret_cast<__attribute__((address_space(3))) void*>(
            reinterpret_cast<uintptr_t>(l)),
        16, 0, 0);
}
__device__ inline void stage4(const float* g, float* l) {
    __builtin_amdgcn_global_load_lds(
        reinterpret_cast<const __attribute__((address_space(1))) void*>(
            reinterpret_cast<uintptr_t>(g)),
        reinterpret_cast<__attribute__((address_space(3))) void*>(
            reinterpret_cast<uintptr_t>(l)),
        4, 0, 0);
}

// mask dtype detection (uniform across grid): 0=int32, 1=fp32, 2=byte bool
__device__ inline int detect_mask_mode(const void* mask_raw, int lane) {
    const unsigned int* mi = (const unsigned int*)mask_raw;
    unsigned int pv = mi[lane];
    float        pf = __uint_as_float(pv);
    bool allint = __all(pv <= 1u) != 0;
    bool allflt = __all(pf == 0.0f || pf == 1.0f) != 0;
    return allint ? 0 : (allflt ? 1 : 2);
}

__device__ inline unsigned long long load_mask_ballot(
    const void* mask_raw, int mode, int n, int lane)
{
    bool mv = false;
    if (lane < SEQ_LEN) {
        size_t off = (size_t)n * SEQ_LEN + lane;
        if (mode == 0)      mv = ((const int*)mask_raw)[off] != 0;
        else if (mode == 1) mv = ((const float*)mask_raw)[off] != 0.0f;
        else                mv = ((const uint8_t*)mask_raw)[off] != 0;
    }
    return __ballot(mv);
}

// ---------------------------------------------------------------------------
// Kernel 1: one wave per sequence. The wave DMAs its whole 12.8 KB sequence
// into a wave-private LDS slice (12x1KB + 2x256B ops, all in flight while the
// wave waits at vmcnt(0)), then computes wt and scatters into num/den.
// LDS 4x12.8 KB = 51.2 KB/block -> 3 blocks/CU = 12 waves/CU; waiting waves
// keep ~75 KB/CU of HBM reads outstanding (need ~9.2 KB to cover latency).
// ---------------------------------------------------------------------------
__global__ __launch_bounds__(256) void wt_scatter_kernel(
    const float* __restrict__ R, const void* __restrict__ mask_raw,
    const float* __restrict__ w,
    const int* __restrict__ users, const int* __restrict__ items,
    const float* __restrict__ item_emb,
    const float* __restrict__ alpha_p, const float* __restrict__ beta_p,
    const float* __restrict__ gamma_p,
    float* __restrict__ num, float* __restrict__ den, int num_seq)
{
    __shared__ float lds[4][SEQ_FLOATS];          // 51.2 KB, wave-private slices

    int wave = (blockIdx.x * blockDim.x + threadIdx.x) >> 6;
    int lane = threadIdx.x & 63;
    int wib  = threadIdx.x >> 6;
    if (wave >= num_seq) return;                  // whole waves retire together
    const int n = wave;

    const float* Rn  = R + (size_t)n * SEQ_FLOATS;
    float* lbase = &lds[wib][0];

    // ---- issue the full-sequence DMA first (BW-critical path) ----
    #pragma unroll
    for (int j = 0; j < 12; ++j)
        stage16(Rn + j * 256 + lane * 4, lbase + j * 256);   // floats [256j,256j+256)
    stage4(Rn + 3072 + lane, lbase + 3072);                  // steps 48
    stage4(Rn + 3136 + lane, lbase + 3136);                  // step 49

    // ---- overlap scalar/mask/table loads with the DMA ----
    const int u  = users[n];
    const int it = items[n];
    const int mode = detect_mask_mode(mask_raw, lane);
    unsigned long long mbits = load_mask_ballot(mask_raw, mode, n, lane);
    const float alpha = alpha_p[0];
    const float beta  = beta_p[0];
    const float gamma = gamma_p[0];
    const int f4 = lane & 15;   // which float4 of the 64 features
    const int sg = lane >> 4;   // which of 4 concurrent steps
    const f32x4 w4 = *reinterpret_cast<const f32x4*>(w + 4 * f4);
    const float2 q = reinterpret_cast<const float2*>(item_emb + (size_t)it * EMB_DIM)[lane];

    // all DMA (and the loads above) complete; slices are wave-private -> no barrier
    asm volatile("s_waitcnt vmcnt(0)" ::: "memory");

    float acc = 0.0f;   // identical across the 16 lanes of a step-group
    float cnt = 0.0f;

    #pragma unroll
    for (int s0 = 0; s0 < SEQ_LEN; s0 += 4) {
        int s = s0 + sg;
        bool valid = (s < SEQ_LEN);
        int sa = valid ? s : 0;                   // clamp: keep ds_read in-slice
        // wave reads 1 KB contiguous from its slice -> conflict-free ds_read_b128
        f32x4 x = *reinterpret_cast<const f32x4*>(lbase + sa * N_FEAT + 4 * f4);
        float d = x.x * w4.x + x.y * w4.y + x.z * w4.z + x.w * w4.w;
        // butterfly over the 16 lanes sharing this step
        d += __shfl_xor(d, 1);
        d += __shfl_xor(d, 2);
        d += __shfl_xor(d, 4);
        d += __shfl_xor(d, 8);
        if (valid && ((mbits >> s) & 1ULL)) {
            float Wv = fmaxf(d, TAU);
            acc += (alpha == 1.0f) ? Wv : powf(Wv, alpha);
            cnt += 1.0f;
        }
    }
    // sum the 4 step-groups; afterwards ALL lanes hold the full totals
    acc += __shfl_xor(acc, 16);
    acc += __shfl_xor(acc, 32);
    cnt += __shfl_xor(cnt, 16);
    cnt += __shfl_xor(cnt, 32);

    float W_alpha = (alpha == 1.0f) ? acc : powf(acc, 1.0f / alpha);
    float R_beta  = (beta  == 1.0f) ? cnt : powf(cnt, beta);
    float base    = W_alpha * R_beta;
    float wt      = (gamma == 1.0f) ? base : powf(base, gamma);

    // fused scatter: each lane owns 2 emb dims (q preloaded above)
    float* numrow = num + (size_t)u * EMB_DIM;
    atomicAdd(&numrow[2 * lane],     wt * q.x);
    atomicAdd(&numrow[2 * lane + 1], wt * q.y);
    if (lane == 0) atomicAdd(&den[u], wt);
}

// ---------------------------------------------------------------------------
// Kernel 2: r[n] = dot(num[u], q[n]) / den[u].  One wave per sequence;
// item_emb/num reads are L2/L3-warm after kernel 1.
// ---------------------------------------------------------------------------
__global__ __launch_bounds__(512) void final_kernel(
    const int* __restrict__ users, const int* __restrict__ items,
    const float* __restrict__ item_emb,
    const float* __restrict__ num, const float* __restrict__ den,
    float* __restrict__ r, int num_seq)
{
    int wave = (blockIdx.x * blockDim.x + threadIdx.x) >> 6;
    int lane = threadIdx.x & 63;
    if (wave >= num_seq) return;
    const int n = wave;

    int u  = users[n];
    int it = items[n];
    float dv = den[u];   // issue early; latency hides under the reduction
    float2 q = reinterpret_cast<const float2*>(item_emb + (size_t)it * EMB_DIM)[lane];
    float2 p = reinterpret_cast<const float2*>(num + (size_t)u * EMB_DIM)[lane];
    float dot = q.x * p.x + q.y * p.y;
    dot += __shfl_xor(dot, 1);
    dot += __shfl_xor(dot, 2);
    dot += __shfl_xor(dot, 4);
    dot += __shfl_xor(dot, 8);
    dot += __shfl_xor(dot, 16);
    dot += __shfl_xor(dot, 32);
    if (lane == 0) r[n] = dot / dv;
}

extern "C" void kernel_launch(void* const* d_in, const int* in_sizes, int n_in,
                              void* d_out, int out_size, void* d_ws, size_t ws_size,
                              hipStream_t stream)
{
    const int*   users    = (const int*)d_in[0];
    const int*   items    = (const int*)d_in[1];
    const float* R_ui     = (const float*)d_in[2];
    const void*  mask     = d_in[3];              // dtype detected on device
    const float* w        = (const float*)d_in[4];
    const float* item_emb = (const float*)d_in[5];
    const float* alpha    = (const float*)d_in[6];
    const float* beta     = (const float*)d_in[7];
    const float* gamma    = (const float*)d_in[8];

    const int num_seq = in_sizes[0];          // 100000
    float* num = (float*)d_ws;                              // [N_USERS][EMB_DIM]
    float* den = (float*)d_ws + (size_t)N_USERS * EMB_DIM;  // [N_USERS]

    // zero the per-user accumulators (graph-capture-safe async memset)
    (void)hipMemsetAsync(d_ws, 0,
                         ((size_t)N_USERS * EMB_DIM + N_USERS) * sizeof(float),
                         stream);

    {   // kernel 1 (LDS-staged wt + scatter): one wave/sequence, 4 waves/block
        int waves_per_block = 4;
        int blocks = (num_seq + waves_per_block - 1) / waves_per_block;
        wt_scatter_kernel<<<blocks, 256, 0, stream>>>(R_ui, mask, w, users, items,
                                                      item_emb, alpha, beta, gamma,
                                                      num, den, num_seq);
    }
    {   // kernel 2: one wave per sequence, 8 waves/block
        int waves_per_block = 8;
        int blocks = (num_seq + waves_per_block - 1) / waves_per_block;
        final_kernel<<<blocks, 512, 0, stream>>>(users, items, item_emb,
                                                 num, den, (float*)d_out, num_seq);
    }
}

// Round 9
// 273.362 us; speedup vs baseline: 1.1721x; 1.1721x over previous
//
#include <hip/hip_runtime.h>
#include <hip/hip_bf16.h>
#include <stdint.h>

#define N_USERS   10000
#define N_ITEMS   100000
#define N_FEAT    64
#define EMB_DIM   128
#define SEQ_LEN   50
#define TAU       0.01f
#define SEQ_FLOATS (SEQ_LEN * N_FEAT)   // 3200 floats = 12.8 KB per sequence

typedef float f32x4 __attribute__((ext_vector_type(4)));
typedef float f32x2 __attribute__((ext_vector_type(2)));

__device__ __forceinline__ f32x4 nt_load4(const float* p) {
    return __builtin_nontemporal_load(reinterpret_cast<const f32x4*>(p));
}
__device__ __forceinline__ f32x2 nt_load2(const float* p) {
    return __builtin_nontemporal_load(reinterpret_cast<const f32x2*>(p));
}

// mask dtype detection (uniform across grid): 0=int32, 1=fp32, 2=byte bool
__device__ __forceinline__ int detect_mask_mode(const void* mask_raw, int lane) {
    const unsigned int* mi = (const unsigned int*)mask_raw;
    unsigned int pv = mi[lane];
    float        pf = __uint_as_float(pv);
    bool allint = __all(pv <= 1u) != 0;
    bool allflt = __all(pf == 0.0f || pf == 1.0f) != 0;
    return allint ? 0 : (allflt ? 1 : 2);
}

__device__ __forceinline__ unsigned long long load_mask_ballot(
    const void* mask_raw, int mode, int n, int lane)
{
    bool mv = false;
    if (lane < SEQ_LEN) {
        size_t off = (size_t)n * SEQ_LEN + lane;
        if (mode == 0)      mv = ((const int*)mask_raw)[off] != 0;
        else if (mode == 1) mv = ((const float*)mask_raw)[off] != 0.0f;
        else                mv = ((const uint8_t*)mask_raw)[off] != 0;
    }
    return __ballot(mv);
}

// per-sequence register buffer (all indices compile-time constant -> VGPRs)
struct SeqRegs {
    f32x4 v[12];              // floats [0,3072): steps 0..47, 1 KB/wave per elt
    f32x2 t;                  // floats [3072,3200): steps 48,49
    f32x2 q;                  // this seq's item_emb row, 2 dims per lane
    int u, it;
    unsigned long long mb;    // mask ballot (uniform)
};

// ---- pipeline stage 1: issue all loads for sequence n ----------------------
__device__ __forceinline__ void load_seq(
    int n, int lane, const float* __restrict__ R,
    const void* __restrict__ mask_raw, int mode,
    const int* __restrict__ users, const int* __restrict__ items,
    const float* __restrict__ item_emb, SeqRegs& s)
{
    const float* Rn = R + (size_t)n * SEQ_FLOATS;
    #pragma unroll
    for (int j = 0; j < 12; ++j)                 // wave covers 1 KB per j
        s.v[j] = nt_load4(Rn + j * 256 + 4 * lane);
    s.t  = nt_load2(Rn + 3072 + 2 * lane);       // steps 48,49
    s.u  = users[n];
    s.it = items[n];
    s.mb = load_mask_ballot(mask_raw, mode, n, lane);
    s.q  = *reinterpret_cast<const f32x2*>(item_emb + (size_t)s.it * EMB_DIM + 2 * lane);
}

// ---- pipeline stage 2: compute wt and scatter ------------------------------
// main loop: step = 4j + (lane>>4), features 4*(lane&15) -> w4
// tail:      step = 48 + (lane>>5), features 2*(lane&31) -> wt2
__device__ __forceinline__ void compute_scatter(
    const SeqRegs& s, int lane, f32x4 w4, f32x2 wt2,
    float alpha, float beta, float gamma,
    float* __restrict__ num, float* __restrict__ den)
{
    const int sg = lane >> 4;
    float acc = 0.0f;

    #pragma unroll
    for (int j = 0; j < 12; ++j) {
        float d = s.v[j].x * w4.x + s.v[j].y * w4.y
                + s.v[j].z * w4.z + s.v[j].w * w4.w;
        d += __shfl_xor(d, 1);
        d += __shfl_xor(d, 2);
        d += __shfl_xor(d, 4);
        d += __shfl_xor(d, 8);
        int step = 4 * j + sg;
        if ((s.mb >> step) & 1ULL) {
            float Wv = fmaxf(d, TAU);
            acc += (alpha == 1.0f) ? Wv : powf(Wv, alpha);
        }
    }
    acc += __shfl_xor(acc, 16);
    acc += __shfl_xor(acc, 32);

    // tail steps 48 (lanes 0-31) and 49 (lanes 32-63): 32-lane reduce
    float dt = s.t.x * wt2.x + s.t.y * wt2.y;
    dt += __shfl_xor(dt, 1);
    dt += __shfl_xor(dt, 2);
    dt += __shfl_xor(dt, 4);
    dt += __shfl_xor(dt, 8);
    dt += __shfl_xor(dt, 16);
    int ts = 48 + (lane >> 5);
    float c = 0.0f;
    if ((s.mb >> ts) & 1ULL) {
        float Wv = fmaxf(dt, TAU);
        c = (alpha == 1.0f) ? Wv : powf(Wv, alpha);
    }
    acc += c + __shfl_xor(c, 32);

    float cnt = (float)__popcll(s.mb & ((1ULL << SEQ_LEN) - 1));

    float W_alpha = (alpha == 1.0f) ? acc : powf(acc, 1.0f / alpha);
    float R_beta  = (beta  == 1.0f) ? cnt : powf(cnt, beta);
    float base    = W_alpha * R_beta;
    float wt      = (gamma == 1.0f) ? base : powf(base, gamma);

    float* numrow = num + (size_t)s.u * EMB_DIM;
    atomicAdd(&numrow[2 * lane],     wt * s.q.x);
    atomicAdd(&numrow[2 * lane + 1], wt * s.q.y);
    if (lane == 0) atomicAdd(&den[s.u], wt);
}

// ---------------------------------------------------------------------------
// Kernel 1: grid-stride, 2-deep software pipeline (load seq k+1 while
// computing seq k). 8192 waves -> ~12 seqs/wave; named A/B register buffers.
// ---------------------------------------------------------------------------
__global__ __launch_bounds__(256) void wt_scatter_kernel(
    const float* __restrict__ R, const void* __restrict__ mask_raw,
    const float* __restrict__ w,
    const int* __restrict__ users, const int* __restrict__ items,
    const float* __restrict__ item_emb,
    const float* __restrict__ alpha_p, const float* __restrict__ beta_p,
    const float* __restrict__ gamma_p,
    float* __restrict__ num, float* __restrict__ den, int num_seq)
{
    const int lane   = threadIdx.x & 63;
    const int gwave  = (blockIdx.x * blockDim.x + threadIdx.x) >> 6;
    const int nwaves = (gridDim.x * blockDim.x) >> 6;

    const int mode = detect_mask_mode(mask_raw, lane);
    const float alpha = alpha_p[0];
    const float beta  = beta_p[0];
    const float gamma = gamma_p[0];

    const f32x4 w4  = *reinterpret_cast<const f32x4*>(w + 4 * (lane & 15));
    const f32x2 wt2 = *reinterpret_cast<const f32x2*>(w + 2 * (lane & 31));

    int n = gwave;
    if (n >= num_seq) return;

    SeqRegs A, B;
    load_seq(n, lane, R, mask_raw, mode, users, items, item_emb, A);

    while (true) {
        int n1 = n + nwaves;
        if (n1 < num_seq)
            load_seq(n1, lane, R, mask_raw, mode, users, items, item_emb, B);
        compute_scatter(A, lane, w4, wt2, alpha, beta, gamma, num, den);
        if (n1 >= num_seq) break;

        int n2 = n1 + nwaves;
        if (n2 < num_seq)
            load_seq(n2, lane, R, mask_raw, mode, users, items, item_emb, A);
        compute_scatter(B, lane, w4, wt2, alpha, beta, gamma, num, den);
        if (n2 >= num_seq) break;

        n = n2;
    }
}

// ---------------------------------------------------------------------------
// Kernel 2: r[n] = dot(num[u], q[n]) / den[u].  One wave per sequence;
// item_emb/num reads are L2/L3-warm after kernel 1.
// ---------------------------------------------------------------------------
__global__ __launch_bounds__(512) void final_kernel(
    const int* __restrict__ users, const int* __restrict__ items,
    const float* __restrict__ item_emb,
    const float* __restrict__ num, const float* __restrict__ den,
    float* __restrict__ r, int num_seq)
{
    int wave = (blockIdx.x * blockDim.x + threadIdx.x) >> 6;
    int lane = threadIdx.x & 63;
    if (wave >= num_seq) return;
    const int n = wave;

    int u  = users[n];
    int it = items[n];
    float dv = den[u];   // issue early; latency hides under the reduction
    float2 q = reinterpret_cast<const float2*>(item_emb + (size_t)it * EMB_DIM)[lane];
    float2 p = reinterpret_cast<const float2*>(num + (size_t)u * EMB_DIM)[lane];
    float dot = q.x * p.x + q.y * p.y;
    dot += __shfl_xor(dot, 1);
    dot += __shfl_xor(dot, 2);
    dot += __shfl_xor(dot, 4);
    dot += __shfl_xor(dot, 8);
    dot += __shfl_xor(dot, 16);
    dot += __shfl_xor(dot, 32);
    if (lane == 0) r[n] = dot / dv;
}

extern "C" void kernel_launch(void* const* d_in, const int* in_sizes, int n_in,
                              void* d_out, int out_size, void* d_ws, size_t ws_size,
                              hipStream_t stream)
{
    const int*   users    = (const int*)d_in[0];
    const int*   items    = (const int*)d_in[1];
    const float* R_ui     = (const float*)d_in[2];
    const void*  mask     = d_in[3];              // dtype detected on device
    const float* w        = (const float*)d_in[4];
    const float* item_emb = (const float*)d_in[5];
    const float* alpha    = (const float*)d_in[6];
    const float* beta     = (const float*)d_in[7];
    const float* gamma    = (const float*)d_in[8];

    const int num_seq = in_sizes[0];          // 100000
    float* num = (float*)d_ws;                              // [N_USERS][EMB_DIM]
    float* den = (float*)d_ws + (size_t)N_USERS * EMB_DIM;  // [N_USERS]

    // zero the per-user accumulators (graph-capture-safe async memset)
    (void)hipMemsetAsync(d_ws, 0,
                         ((size_t)N_USERS * EMB_DIM + N_USERS) * sizeof(float),
                         stream);

    {   // kernel 1: grid-stride pipelined, 2048 blocks x 4 waves = 8192 waves
        wt_scatter_kernel<<<2048, 256, 0, stream>>>(R_ui, mask, w, users, items,
                                                    item_emb, alpha, beta, gamma,
                                                    num, den, num_seq);
    }
    {   // kernel 2: one wave per sequence, 8 waves/block
        int waves_per_block = 8;
        int blocks = (num_seq + waves_per_block - 1) / waves_per_block;
        final_kernel<<<blocks, 512, 0, stream>>>(users, items, item_emb,
                                                 num, den, (float*)d_out, num_seq);
    }
}